// Round 6
// baseline (565.092 us; speedup 1.0000x reference)
//
#include <hip/hip_runtime.h>

// FirstOrderCondRNN: B=256 batches, T=61 (60 scan steps).
// N_MBON=20, N_FBN=60, N_DAN=20, N_KC=200, N_RECUR=100.
// Outputs (flat, concat): r_series (61,B,100), W_series (61,B,20,200),
//                         wt_series (61,B,20,200), readout (61,B).
//
// R6: break the 1-block/CU lockstep (the one invariant all 5 null rounds
// shared). Two independent blocks per CU:
//  - grid = 2B; pair (p, h): BOTH blocks compute batch p's full trajectory
//    (bit-identical FP); each stores half the W/wt chunks (h=0: c<500,
//    h=1: c>=500; r/readout stored by h=0). Total HBM bytes unchanged;
//    two independent barrier domains per CU overlap each other's latency.
//  - LDS 93->68 KB (co-residency prereq): s_rk replaced by a 24-row
//    rolling window (19.2 KB) refilled 8 rows every 8 steps from global
//    (L2-resident; refill writes provably-dead slots, ordered by the
//    existing lgkmcnt barriers).
//  - keeps: WRSTR=108, bar_lds (no vmcnt drain), nt stores, rk reg-carry.

#define NKC   200
#define NREC  100
#define TSTEP 61
#define NSTEP 60
#define WRSTR 108   // padded Wr row stride (16B-aligned rows, full bank coverage)
#define PSTR  52    // padded partial row stride
#define NTHR  512
#define WN    24    // rolling r_kc window rows

typedef float vfloat4 __attribute__((ext_vector_type(4)));

// Workgroup barrier that waits only on LDS ops (lgkmcnt), leaving global
// stores in flight (no vmcnt drain). sched_barrier(0) pins program order.
__device__ __forceinline__ void bar_lds() {
    __builtin_amdgcn_sched_barrier(0);
    asm volatile("s_waitcnt lgkmcnt(0)");
    __builtin_amdgcn_s_barrier();
    __builtin_amdgcn_sched_barrier(0);
}

__device__ __forceinline__ void nt_store4(float* p, float4 v) {
    vfloat4 t;
    t.x = v.x; t.y = v.y; t.z = v.z; t.w = v.w;
    __builtin_nontemporal_store(t, (vfloat4*)p);
}
__device__ __forceinline__ void nt_store1(float* p, float v) {
    __builtin_nontemporal_store(v, p);
}

__global__ __launch_bounds__(NTHR, 4) void cond_rnn_kernel(
    const float* __restrict__ r_kc, const float* __restrict__ r_ext,
    const float* __restrict__ timev, const float* __restrict__ W0_W,
    const float* __restrict__ W0_w, const float* __restrict__ W_recur,
    const float* __restrict__ W_ext, const float* __restrict__ bias,
    const float* __restrict__ W_readout, float* __restrict__ out, int B)
{
    const int b   = blockIdx.x >> 1;          // batch (pair index)
    const int h   = blockIdx.x & 1;           // store-half: 0 -> c<500, 1 -> c>=500
    const int tid = threadIdx.x;
    const float dt  = timev[1] - timev[0];    // 0.5
    const float dtw = dt / 5.0f;              // dt / TAU_W

    __shared__ __align__(16) float s_rkw[WN * NKC];     // rolling [t%24][k], 19.2 KB
    __shared__ __align__(16) float s_re[128];           // [e][t] (2*61)
    __shared__ __align__(16) float s_Wr[NREC * WRSTR];  // 43.2 KB
    __shared__ __align__(16) float s_Wro[32];
    __shared__ __align__(16) float s_r[2][112];         // double-buffered rates
    __shared__ __align__(16) float s_rbd[32];
    __shared__ __align__(16) float s_part[20 * PSTR];   // I_kc partials

    // ---------------- init: stage batch inputs into LDS ----------------
    const float* rk_b = r_kc + (size_t)b * (NKC * TSTEP);   // [k][t] layout
    for (int f = tid; f < WN * NKC; f += NTHR) {            // rows 0..23
        int r = f / NKC, k = f - r * NKC;
        s_rkw[r * NKC + k] = rk_b[k * TSTEP + r];
    }
    const float* re_b = r_ext + (size_t)b * (2 * TSTEP);
    if (tid < 2 * TSTEP) s_re[tid] = re_b[tid];
    for (int f = tid; f < NREC * NREC; f += NTHR) {
        int s = f / NREC, j = f - s * NREC;
        float v = W_recur[f];
        if (s < 20 && j >= 80) v = 0.f;            // Wr[:n_mbon, -n_dan:] = 0
        s_Wr[s * WRSTR + j] = v;
    }
    if (tid < 20)  s_Wro[tid] = W_readout[tid];
    if (tid < 100) s_r[0][tid] = (tid < 20) ? 0.f : 0.1f;
    if (tid < 20)  s_rbd[tid] = 0.1f;

    float my_bias = 0.f, we0 = 0.f, we1 = 0.f;
    if (tid < 100) my_bias = bias[tid];
    if (tid >= 20 && tid < 80) { we0 = W_ext[(tid - 20) * 2]; we1 = W_ext[(tid - 20) * 2 + 1]; }
    float rbd_mine = 0.1f;
    float r_mine   = (tid < 20) ? 0.f : 0.1f;

    // output sections
    float* out_r  = out;                              // [61][B][100]
    float* out_W  = out + (size_t)TSTEP * B * 100;    // [61][B][4000]
    float* out_wt = out_W + (size_t)TSTEP * B * 4000; // [61][B][4000]
    float* out_ro = out_wt + (size_t)TSTEP * B * 4000;// [61][B]

    // W / wt / rbk in registers: 2 float4 chunks per thread (chunk c = tid+512*i)
    float4 Wreg[2], wtreg[2], rbkreg[2], rkc[2];
    const float* W0Wb = W0_W + (size_t)b * 4000;
    const float* W0wb = W0_w + (size_t)b * 4000;
    #pragma unroll
    for (int i = 0; i < 2; ++i) {
        int c = tid + NTHR * i;
        if (c < 1000) {
            Wreg[i]  = *(const float4*)(W0Wb + 4 * c);
            wtreg[i] = *(const float4*)(W0wb + 4 * c);
            if ((c < 500) == (h == 0)) {                        // my store half
                nt_store4(out_W  + (size_t)b * 4000 + 4 * c, Wreg[i]);   // t=0
                nt_store4(out_wt + (size_t)b * 4000 + 4 * c, wtreg[i]);
            }
        }
    }
    if (h == 0 && tid < 100) nt_store1(out_r + (size_t)b * 100 + tid, r_mine);

    __syncthreads();

    // initial rbk = rk[:,0]; initial I_kc partials = dot(W0, rk_0);
    // rkc carries rk row `it` for this thread's chunks.
    #pragma unroll
    for (int i = 0; i < 2; ++i) {
        int c = tid + NTHR * i;
        if (c < 1000) {
            int k0 = (4 * c) % NKC;
            int m  = c / 50;
            float4 rk0 = *(const float4*)(s_rkw + k0);   // t = 0 row (slot 0)
            rbkreg[i] = rk0;
            rkc[i]    = rk0;
            float4 w = Wreg[i];
            s_part[m * PSTR + (c % 50)] =
                w.x * rk0.x + w.y * rk0.y + w.z * rk0.z + w.w * rk0.w;
        }
    }
    if (h == 0 && tid == 255) {
        float ro = 0.f;
        #pragma unroll
        for (int mm = 0; mm < 20; ++mm) ro += s_Wro[mm] * s_r[0][mm];
        nt_store1(out_ro + b, ro);   // t=0 readout
    }
    __syncthreads();

    // ---------------- time loop ----------------
    for (int it = 0; it < NSTEP; ++it) {
        const int cur = it & 1, nxt = cur ^ 1;

        // Phase A: drive = bias + Wr·r + I_tot ; r_new ; rbd_new
        if (tid < 100) {
            float acc = my_bias;
            if (tid < 20) {                       // MBON: + I_kc from partials
                const float* pp = s_part + tid * PSTR;
                #pragma unroll
                for (int q4 = 0; q4 < 12; ++q4) {
                    float4 p4 = *(const float4*)(pp + 4 * q4);
                    acc += p4.x + p4.y + p4.z + p4.w;
                }
                acc += pp[48] + pp[49];
            } else if (tid < 80) {                // FBN: + W_ext · re_t
                acc = fmaf(we0, s_re[it], acc);
                acc = fmaf(we1, s_re[TSTEP + it], acc);
            }
            const float* wr = s_Wr + tid * WRSTR;
            #pragma unroll
            for (int j4 = 0; j4 < 25; ++j4) {
                float4 w4 = *(const float4*)(wr + 4 * j4);
                float4 r4 = *(const float4*)(&s_r[cur][4 * j4]);
                acc = fmaf(w4.x, r4.x, acc); acc = fmaf(w4.y, r4.y, acc);
                acc = fmaf(w4.z, r4.z, acc); acc = fmaf(w4.w, r4.w, acc);
            }
            float drive = acc > 0.f ? acc : 0.f;  // relu
            float rn = r_mine + dt * (drive - r_mine);   // TAU_R = 1
            r_mine = rn;
            s_r[nxt][tid] = rn;
            if (h == 0)
                nt_store1(out_r + (size_t)(it + 1) * B * 100 + (size_t)b * 100 + tid, rn);
            if (tid >= 80) {                      // DAN: rbd update
                rbd_mine += (rn - rbd_mine) * dtw;
                s_rbd[tid - 80] = rbd_mine;
            }
        }

        // Rolling-window refill (every 8 steps): rows [it+17, it+24] clamped.
        // Overwrites slots of rows [it-7, it] — all dead (last read in E of
        // step it-1, closed by that step's end barrier). Row it+1 (needed by
        // THIS step's E) is slot (it+1)%24, not among targets. Visibility:
        // ds_writes complete at the lgkmcnt(0) barrier below; earliest read
        // of these rows is >= 9 steps later.
        if ((it & 7) == 6) {
            int t0 = it + 17;
            int nrows = TSTEP - t0; if (nrows > 8) nrows = 8;
            if (nrows > 0) {
                for (int f = tid; f < nrows * NKC; f += NTHR) {
                    int rr = f / NKC, k = f - rr * NKC;
                    int t  = t0 + rr;
                    s_rkw[(t % WN) * NKC + k] = rk_b[k * TSTEP + t];
                }
            }
        }
        bar_lds();

        // Phase E: rbk / wt / W updates, next-step partials, global stores
        float* oW  = out_W  + (size_t)(it + 1) * B * 4000 + (size_t)b * 4000;
        float* owt = out_wt + (size_t)(it + 1) * B * 4000 + (size_t)b * 4000;
        const float* rk_nx = s_rkw + ((it + 1) % WN) * NKC;
        #pragma unroll
        for (int i = 0; i < 2; ++i) {
            int c = tid + NTHR * i;
            if (c < 1000) {
                int k0 = (4 * c) % NKC;
                int m  = c / 50;
                float4 rk4 = rkc[i];                        // carried row `it`
                float4 rkn = *(const float4*)(rk_nx + k0);  // row `it+1`
                rkc[i] = rkn;
                float rbdn = s_rbd[m];
                float rdan = s_r[nxt][80 + m];
                float4 rb = rbkreg[i];
                rb.x += (rk4.x - rb.x) * dtw;  rb.y += (rk4.y - rb.y) * dtw;
                rb.z += (rk4.z - rb.z) * dtw;  rb.w += (rk4.w - rb.w) * dtw;
                rbkreg[i] = rb;
                float4 wt = wtreg[i];
                wt.x = fmaf(rbdn * rk4.x - rdan * rb.x, dt, wt.x);
                wt.y = fmaf(rbdn * rk4.y - rdan * rb.y, dt, wt.y);
                wt.z = fmaf(rbdn * rk4.z - rdan * rb.z, dt, wt.z);
                wt.w = fmaf(rbdn * rk4.w - rdan * rb.w, dt, wt.w);
                wtreg[i] = wt;
                float4 w = Wreg[i];
                w.x += (wt.x - w.x) * dtw;  w.y += (wt.y - w.y) * dtw;
                w.z += (wt.z - w.z) * dtw;  w.w += (wt.w - w.w) * dtw;
                w.x = fminf(fmaxf(w.x, 0.f), 0.05f);
                w.y = fminf(fmaxf(w.y, 0.f), 0.05f);
                w.z = fminf(fmaxf(w.z, 0.f), 0.05f);
                w.w = fminf(fmaxf(w.w, 0.f), 0.05f);
                Wreg[i] = w;
                // partial dot for NEXT step's I_kc (uses rk at it+1)
                s_part[m * PSTR + (c % 50)] =
                    w.x * rkn.x + w.y * rkn.y + w.z * rkn.z + w.w * rkn.w;
                if ((c < 500) == (h == 0)) {                // my store half
                    nt_store4(owt + 4 * c, wt);
                    nt_store4(oW  + 4 * c, w);
                }
            }
        }
        if (h == 0 && tid == 255) {   // readout from r_new MBONs
            float ro = 0.f;
            #pragma unroll
            for (int mm = 0; mm < 20; ++mm) ro += s_Wro[mm] * s_r[nxt][mm];
            nt_store1(out_ro + (size_t)(it + 1) * B + b, ro);
        }
        bar_lds();
    }
}

extern "C" void kernel_launch(void* const* d_in, const int* in_sizes, int n_in,
                              void* d_out, int out_size, void* d_ws, size_t ws_size,
                              hipStream_t stream) {
    const float* r_kc      = (const float*)d_in[0];
    const float* r_ext     = (const float*)d_in[1];
    const float* timev     = (const float*)d_in[2];
    // d_in[3] = n_batch (int scalar) — shape derived from in_sizes instead
    const float* W0_W      = (const float*)d_in[4];
    const float* W0_w      = (const float*)d_in[5];
    const float* W_recur   = (const float*)d_in[6];
    const float* W_ext     = (const float*)d_in[7];
    const float* bias      = (const float*)d_in[8];
    const float* W_readout = (const float*)d_in[9];

    const int B = in_sizes[0] / (NKC * TSTEP);   // 256
    cond_rnn_kernel<<<dim3(2 * B), dim3(NTHR), 0, stream>>>(
        r_kc, r_ext, timev, W0_W, W0_w, W_recur, W_ext, bias, W_readout,
        (float*)d_out, B);
}

// Round 7
// 516.022 us; speedup vs baseline: 1.0951x; 1.0951x over previous
//
#include <hip/hip_runtime.h>

// FirstOrderCondRNN: B=256 batches, T=61 (60 scan steps).
// One block per batch; all recurrent state on-chip.
// N_MBON=20, N_FBN=60, N_DAN=20, N_KC=200, N_RECUR=100.
// Outputs (flat, concat): r_series (61,B,100), W_series (61,B,20,200),
//                         wt_series (61,B,20,200), readout (61,B).
//
// R7: Wr in REGISTERS (cycle-reduction round). Ledger R1-R6 falsified
// drain/TLP/banks/locality/co-residency; costs track cycle-count at an
// effective core clock ~1 GHz, so the lever is removing cycles. Phase A's
// 25 ds_read_b128 of Wr per thread (~50 wave-instrs/step/CU, ~600-800 cyc)
// move to a per-thread register row wrreg[25] (tid<100; ~180 VGPR total,
// still 8 waves/CU). s_Wr LDS (-43KB) and its staging are deleted.
// FP order unchanged -> bit-identical (absmax must stay exactly 0.25).
// Keeps R5 base: 512 thr, WRSTR gone, bar_lds (no vmcnt drain), XCD
// swizzle, nt stores, full s_rk stage, rk register carry.

#define NKC   200
#define NREC  100
#define TSTEP 61
#define NSTEP 60
#define PSTR  52    // padded partial row stride
#define NTHR  512

typedef float vfloat4 __attribute__((ext_vector_type(4)));

// Workgroup barrier that waits only on LDS ops (lgkmcnt), leaving global
// stores in flight (no vmcnt drain). sched_barrier(0) pins program order.
__device__ __forceinline__ void bar_lds() {
    __builtin_amdgcn_sched_barrier(0);
    asm volatile("s_waitcnt lgkmcnt(0)");
    __builtin_amdgcn_s_barrier();
    __builtin_amdgcn_sched_barrier(0);
}

__device__ __forceinline__ void nt_store4(float* p, float4 v) {
    vfloat4 t;
    t.x = v.x; t.y = v.y; t.z = v.z; t.w = v.w;
    __builtin_nontemporal_store(t, (vfloat4*)p);
}
__device__ __forceinline__ void nt_store1(float* p, float v) {
    __builtin_nontemporal_store(v, p);
}

__global__ __launch_bounds__(NTHR, 1) void cond_rnn_kernel(
    const float* __restrict__ r_kc, const float* __restrict__ r_ext,
    const float* __restrict__ timev, const float* __restrict__ W0_W,
    const float* __restrict__ W0_w, const float* __restrict__ W_recur,
    const float* __restrict__ W_ext, const float* __restrict__ bias,
    const float* __restrict__ W_readout, float* __restrict__ out, int B)
{
    // XCD-aware bijective swizzle (B=256, 8 XCDs).
    int b = blockIdx.x;
    if ((B & 7) == 0) {
        const int cpx = B >> 3;                  // blocks per XCD
        b = (blockIdx.x & 7) * cpx + (blockIdx.x >> 3);
    }
    const int tid = threadIdx.x;
    const float dt  = timev[1] - timev[0];   // 0.5
    const float dtw = dt / 5.0f;             // dt / TAU_W

    __shared__ __align__(16) float s_rk[TSTEP * NKC];   // [t][k], 48.8 KB
    __shared__ __align__(16) float s_re[128];           // [e][t] (2*61)
    __shared__ __align__(16) float s_Wro[32];
    __shared__ __align__(16) float s_r[2][112];         // double-buffered rates
    __shared__ __align__(16) float s_rbd[32];
    __shared__ __align__(16) float s_part[20 * PSTR];   // I_kc partials

    // ---------------- init: stage batch inputs into LDS ----------------
    const float* rk_b = r_kc + (size_t)b * (NKC * TSTEP);
    for (int f = tid; f < NKC * TSTEP; f += NTHR) {
        int k = f / TSTEP, t = f - k * TSTEP;
        s_rk[t * NKC + k] = rk_b[f];               // transpose to [t][k]
    }
    const float* re_b = r_ext + (size_t)b * (2 * TSTEP);
    if (tid < 2 * TSTEP) s_re[tid] = re_b[tid];

    // Wr row in registers (tid<100): 25 float4 = 100 VGPR.
    // Same values as the old s_Wr staging: row tid of W_recur (row-major),
    // with Wr[:20, 80:] = 0 applied.
    float4 wrreg[25];
    if (tid < 100) {
        const float* wrow = W_recur + tid * NREC;
        #pragma unroll
        for (int j4 = 0; j4 < 25; ++j4)
            wrreg[j4] = *(const float4*)(wrow + 4 * j4);
        if (tid < 20) {
            #pragma unroll
            for (int j4 = 20; j4 < 25; ++j4) {
                wrreg[j4].x = 0.f; wrreg[j4].y = 0.f;
                wrreg[j4].z = 0.f; wrreg[j4].w = 0.f;
            }
        }
    }

    if (tid < 20)  s_Wro[tid] = W_readout[tid];
    if (tid < 100) s_r[0][tid] = (tid < 20) ? 0.f : 0.1f;
    if (tid < 20)  s_rbd[tid] = 0.1f;

    float my_bias = 0.f, we0 = 0.f, we1 = 0.f;
    if (tid < 100) my_bias = bias[tid];
    if (tid >= 20 && tid < 80) { we0 = W_ext[(tid - 20) * 2]; we1 = W_ext[(tid - 20) * 2 + 1]; }
    float rbd_mine = 0.1f;
    float r_mine   = (tid < 20) ? 0.f : 0.1f;

    // output sections
    float* out_r  = out;                              // [61][B][100]
    float* out_W  = out + (size_t)TSTEP * B * 100;    // [61][B][4000]
    float* out_wt = out_W + (size_t)TSTEP * B * 4000; // [61][B][4000]
    float* out_ro = out_wt + (size_t)TSTEP * B * 4000;// [61][B]

    // W / wt / rbk in registers: 2 float4 chunks per thread (chunk c = tid+512*i)
    float4 Wreg[2], wtreg[2], rbkreg[2], rkc[2];
    const float* W0Wb = W0_W + (size_t)b * 4000;
    const float* W0wb = W0_w + (size_t)b * 4000;
    #pragma unroll
    for (int i = 0; i < 2; ++i) {
        int c = tid + NTHR * i;
        if (c < 1000) {
            Wreg[i]  = *(const float4*)(W0Wb + 4 * c);
            wtreg[i] = *(const float4*)(W0wb + 4 * c);
            nt_store4(out_W  + (size_t)b * 4000 + 4 * c, Wreg[i]);   // t=0 dumps
            nt_store4(out_wt + (size_t)b * 4000 + 4 * c, wtreg[i]);
        }
    }
    if (tid < 100) nt_store1(out_r + (size_t)b * 100 + tid, r_mine);

    __syncthreads();

    // initial rbk = rk[:,0]; initial I_kc partials = dot(W0, rk_0);
    // rkc carries rk row `it` for this thread's chunks.
    #pragma unroll
    for (int i = 0; i < 2; ++i) {
        int c = tid + NTHR * i;
        if (c < 1000) {
            int k0 = (4 * c) % NKC;
            int m  = c / 50;
            float4 rk0 = *(const float4*)(s_rk + k0);   // t = 0 row
            rbkreg[i] = rk0;
            rkc[i]    = rk0;
            float4 w = Wreg[i];
            s_part[m * PSTR + (c % 50)] =
                w.x * rk0.x + w.y * rk0.y + w.z * rk0.z + w.w * rk0.w;
        }
    }
    if (tid == 255) {
        float ro = 0.f;
        #pragma unroll
        for (int mm = 0; mm < 20; ++mm) ro += s_Wro[mm] * s_r[0][mm];
        nt_store1(out_ro + b, ro);   // t=0 readout
    }
    __syncthreads();

    // ---------------- time loop ----------------
    for (int it = 0; it < NSTEP; ++it) {
        const int cur = it & 1, nxt = cur ^ 1;

        // Phase A: drive = bias + Wr·r + I_tot ; r_new ; rbd_new
        if (tid < 100) {
            float acc = my_bias;
            if (tid < 20) {                       // MBON: + I_kc from partials
                const float* pp = s_part + tid * PSTR;
                #pragma unroll
                for (int q4 = 0; q4 < 12; ++q4) {
                    float4 p4 = *(const float4*)(pp + 4 * q4);
                    acc += p4.x + p4.y + p4.z + p4.w;
                }
                acc += pp[48] + pp[49];
            } else if (tid < 80) {                // FBN: + W_ext · re_t
                acc = fmaf(we0, s_re[it], acc);
                acc = fmaf(we1, s_re[TSTEP + it], acc);
            }
            #pragma unroll
            for (int j4 = 0; j4 < 25; ++j4) {
                float4 w4 = wrreg[j4];
                float4 r4 = *(const float4*)(&s_r[cur][4 * j4]);
                acc = fmaf(w4.x, r4.x, acc); acc = fmaf(w4.y, r4.y, acc);
                acc = fmaf(w4.z, r4.z, acc); acc = fmaf(w4.w, r4.w, acc);
            }
            float drive = acc > 0.f ? acc : 0.f;  // relu
            float rn = r_mine + dt * (drive - r_mine);   // TAU_R = 1
            r_mine = rn;
            s_r[nxt][tid] = rn;
            nt_store1(out_r + (size_t)(it + 1) * B * 100 + (size_t)b * 100 + tid, rn);
            if (tid >= 80) {                      // DAN: rbd update
                rbd_mine += (rn - rbd_mine) * dtw;
                s_rbd[tid - 80] = rbd_mine;
            }
        }
        bar_lds();

        // Phase E: rbk / wt / W updates, next-step partials, global stores
        float* oW  = out_W  + (size_t)(it + 1) * B * 4000 + (size_t)b * 4000;
        float* owt = out_wt + (size_t)(it + 1) * B * 4000 + (size_t)b * 4000;
        const float* rk_nx  = s_rk + (it + 1) * NKC;
        #pragma unroll
        for (int i = 0; i < 2; ++i) {
            int c = tid + NTHR * i;
            if (c < 1000) {
                int k0 = (4 * c) % NKC;
                int m  = c / 50;
                float4 rk4 = rkc[i];                        // carried row `it`
                float4 rkn = *(const float4*)(rk_nx + k0);  // row `it+1`
                rkc[i] = rkn;
                float rbdn = s_rbd[m];
                float rdan = s_r[nxt][80 + m];
                float4 rb = rbkreg[i];
                rb.x += (rk4.x - rb.x) * dtw;  rb.y += (rk4.y - rb.y) * dtw;
                rb.z += (rk4.z - rb.z) * dtw;  rb.w += (rk4.w - rb.w) * dtw;
                rbkreg[i] = rb;
                float4 wt = wtreg[i];
                wt.x = fmaf(rbdn * rk4.x - rdan * rb.x, dt, wt.x);
                wt.y = fmaf(rbdn * rk4.y - rdan * rb.y, dt, wt.y);
                wt.z = fmaf(rbdn * rk4.z - rdan * rb.z, dt, wt.z);
                wt.w = fmaf(rbdn * rk4.w - rdan * rb.w, dt, wt.w);
                wtreg[i] = wt;
                float4 w = Wreg[i];
                w.x += (wt.x - w.x) * dtw;  w.y += (wt.y - w.y) * dtw;
                w.z += (wt.z - w.z) * dtw;  w.w += (wt.w - w.w) * dtw;
                w.x = fminf(fmaxf(w.x, 0.f), 0.05f);
                w.y = fminf(fmaxf(w.y, 0.f), 0.05f);
                w.z = fminf(fmaxf(w.z, 0.f), 0.05f);
                w.w = fminf(fmaxf(w.w, 0.f), 0.05f);
                Wreg[i] = w;
                // partial dot for NEXT step's I_kc (uses rk at it+1)
                s_part[m * PSTR + (c % 50)] =
                    w.x * rkn.x + w.y * rkn.y + w.z * rkn.z + w.w * rkn.w;
                nt_store4(owt + 4 * c, wt);
                nt_store4(oW  + 4 * c, w);
            }
        }
        if (tid == 255) {   // readout from r_new MBONs
            float ro = 0.f;
            #pragma unroll
            for (int mm = 0; mm < 20; ++mm) ro += s_Wro[mm] * s_r[nxt][mm];
            nt_store1(out_ro + (size_t)(it + 1) * B + b, ro);
        }
        bar_lds();
    }
}

extern "C" void kernel_launch(void* const* d_in, const int* in_sizes, int n_in,
                              void* d_out, int out_size, void* d_ws, size_t ws_size,
                              hipStream_t stream) {
    const float* r_kc      = (const float*)d_in[0];
    const float* r_ext     = (const float*)d_in[1];
    const float* timev     = (const float*)d_in[2];
    // d_in[3] = n_batch (int scalar) — shape derived from in_sizes instead
    const float* W0_W      = (const float*)d_in[4];
    const float* W0_w      = (const float*)d_in[5];
    const float* W_recur   = (const float*)d_in[6];
    const float* W_ext     = (const float*)d_in[7];
    const float* bias      = (const float*)d_in[8];
    const float* W_readout = (const float*)d_in[9];

    const int B = in_sizes[0] / (NKC * TSTEP);   // 256
    cond_rnn_kernel<<<dim3(B), dim3(NTHR), 0, stream>>>(
        r_kc, r_ext, timev, W0_W, W0_w, W_recur, W_ext, bias, W_readout,
        (float*)d_out, B);
}